// Round 5
// baseline (47.019 us; speedup 1.0000x reference)
//
#include <hip/hip_runtime.h>
#include <math.h>

// LegendreBasis: out[b, nb] = prod_d P_{e[d,nb]}(clip(actions[b,d], -1, 1))
// B=131072, D=8, NB=495, rank=4. Write-bound (~260 MB out).
// Design: basis = U-monomial(dims 0-3) x V-monomial(dims 4-7); 70 monomials
// each (deg<=4). Each lane OWNS one nb: its (a,b) table indices are
// loop-invariant registers (computed once from exps, no program decode).
// Monomial tables stored TRANSPOSED in LDS (UT[a][row], stride 68) so one
// ds_read_b128 fetches 4 consecutive rows' factor. Inner loop per 4 rows:
// 2 b128 LDS + 4 muls + 4 coalesced dword stores.

#define THREADS 512
#define TILE 64        // rows per block
#define TSTR 68        // row stride in UT/VT: %4==0 (16B align), mod 32 == 4

typedef float f32x4 __attribute__((ext_vector_type(4)));

__device__ __forceinline__ int c2i(int n){ return (n < 2) ? 0 : (n*(n-1))>>1; }
__device__ __forceinline__ int c3i(int n){ return (n < 3) ? 0 : (n*(n-1)*(n-2))/6; }
__device__ __forceinline__ int c4i(int n){ return (n < 4) ? 0 : (n*(n-1)*(n-2)*(n-3))/24; }

// rank of (a,b,c,d), sum<=4, nested-loop order (d fastest). Range [0,70).
__device__ __forceinline__ int rank4(int a, int b, int c, int d) {
    return (70 - c4i(8-a)) + (c3i(7-a) - c3i(7-a-b))
         + (c2i(6-a-b) - c2i(6-a-b-c)) + d;
}

__global__ __launch_bounds__(THREADS, 8) void legendre_fast(
    const float* __restrict__ actions,
    const int* __restrict__ exps,
    float* __restrict__ out)
{
    __shared__ float UT[70 * TSTR];   // UT[a*TSTR + row]
    __shared__ float VT[70 * TSTR];   // VT[b*TSTR + row]

    const int t = threadIdx.x;
    const int r0 = blockIdx.x * TILE;

    // ---- phase 1: per-lane (a, b) from exponents (loop-invariant) ----
    int ai = 0, bi = 0;
    if (t < 495) {
        int e0 = exps[0*495+t], e1 = exps[1*495+t];
        int e2 = exps[2*495+t], e3 = exps[3*495+t];
        int e4 = exps[4*495+t], e5 = exps[5*495+t];
        int e6 = exps[6*495+t], e7 = exps[7*495+t];
        ai = rank4(e0, e1, e2, e3);
        bi = rank4(e4, e5, e6, e7);
    }

    // ---- phase 2: build transposed monomial tables (128 threads) ----
    if (t < 2 * TILE) {
        int row = t >> 1, half = t & 1;
        f32x4 xv = *(const f32x4*)(actions + (long long)(r0 + row) * 8 + half * 4);
        float P[4][5];
#pragma unroll
        for (int d = 0; d < 4; ++d) {
            float x = fminf(fmaxf(xv[d], -1.0f), 1.0f);
            P[d][0] = 1.0f; P[d][1] = x;
#pragma unroll
            for (int n = 2; n <= 4; ++n) {
                float fn = (float)n;
                P[d][n] = ((2.0f*fn - 1.0f)/fn) * x * P[d][n-1]
                        - ((fn - 1.0f)/fn) * P[d][n-2];
            }
        }
        float* W = (half ? VT : UT) + row;   // write W[cnt*TSTR]
        int cnt = 0;
#pragma unroll
        for (int a = 0; a <= 4; ++a) { float q0 = P[0][a];
#pragma unroll
            for (int b = 0; b <= 4-a; ++b) { float q1 = q0 * P[1][b];
#pragma unroll
                for (int c = 0; c <= 4-a-b; ++c) { float q2 = q1 * P[2][c];
#pragma unroll
                    for (int d = 0; d <= 4-a-b-c; ++d) {
                        W[cnt * TSTR] = q2 * P[3][d];
                        ++cnt;
                    }
                }
            }
        }
    }
    __syncthreads();

    // ---- main loop: lane owns nb=t; 4 rows per iter via 2x ds_read_b128 ----
    if (t < 495) {
        const float* Urow = &UT[ai * TSTR];
        const float* Vrow = &VT[bi * TSTR];
        float* obase = out + (long long)r0 * 495 + t;
#pragma unroll 4
        for (int q = 0; q < TILE / 4; ++q) {
            f32x4 u = *(const f32x4*)(Urow + 4 * q);
            f32x4 v = *(const f32x4*)(Vrow + 4 * q);
            float* o = obase + (long long)(4 * q) * 495;
            o[0]        = u.x * v.x;
            o[495]      = u.y * v.y;
            o[2 * 495]  = u.z * v.z;
            o[3 * 495]  = u.w * v.w;
        }
    }
}

// Generic fallback: one thread per output element, rolling recurrence.
__global__ void legendre_generic(
    const float* __restrict__ actions,
    const int* __restrict__ exps,
    float* __restrict__ out,
    long long total, int D, int NB)
{
    long long stride = (long long)gridDim.x * blockDim.x;
    for (long long i = (long long)blockIdx.x * blockDim.x + threadIdx.x;
         i < total; i += stride) {
        int nb = (int)(i % NB);
        long long row = i / NB;
        float prod = 1.0f;
        for (int d = 0; d < D; ++d) {
            int e = exps[d * NB + nb];
            float x = actions[row * D + d];
            x = fminf(fmaxf(x, -1.0f), 1.0f);
            float p0 = 1.0f, p1 = x;
            float p = (e == 0) ? 1.0f : x;
            for (int n = 2; n <= e; ++n) {
                float fn = (float)n;
                float pn = ((2.0f*fn - 1.0f)/fn) * x * p1 - ((fn - 1.0f)/fn) * p0;
                p0 = p1; p1 = pn; p = pn;
            }
            prod *= p;
        }
        out[i] = prod;
    }
}

extern "C" void kernel_launch(void* const* d_in, const int* in_sizes, int n_in,
                              void* d_out, int out_size, void* d_ws, size_t ws_size,
                              hipStream_t stream) {
    const float* actions = (const float*)d_in[0];
    const int* exps = (const int*)d_in[1];
    float* out = (float*)d_out;

    long long in0 = in_sizes[0];   // B*D
    long long in1 = in_sizes[1];   // D*NB
    long long osz = out_size;      // B*NB

    int D = (int)(sqrt((double)in0 * (double)in1 / (double)osz) + 0.5);
    if (D < 1) D = 1;
    int NB = (int)(in1 / D);
    int B = (int)(in0 / D);

    bool fast = (D == 8 && NB == 495 &&
                 (long long)B * NB == osz && (long long)B * D == in0 &&
                 (B % TILE) == 0);

    if (fast) {
        legendre_fast<<<B / TILE, THREADS, 0, stream>>>(actions, exps, out);
    } else {
        long long total = osz;
        long long want = (total + 255) / 256;
        int nblk = (want > 8192) ? 8192 : (int)(want > 0 ? want : 1);
        legendre_generic<<<nblk, 256, 0, stream>>>(
            actions, exps, out, total, D, NB);
    }
}